// Round 13
// baseline (1084.592 us; speedup 1.0000x reference)
//
#include <hip/hip_runtime.h>
#include <hip/hip_bf16.h>
#include <cmath>

// GMM E-step: N=131072, K=64, D=256.
// Round 13: corrected period-2 schedule (T3 minimum 2-phase). Double-
// buffered substep PAIRS; per period: [stage next pair] [compute current
// pair: 32 MFMA] [epilogue if k-end] [vmcnt(0)] [barrier]. Stage happens
// after the barrier that retires the pair's previous readers -> no WAR
// race (round 12's bug). 4 barriers/k. A in registers (AGPR), VALU-DPP
// epilogue, ds_add combine, tvec in LDS.

typedef unsigned short ushort_t;
typedef __attribute__((ext_vector_type(4))) float f32x4;
typedef __attribute__((ext_vector_type(8))) short bf16x8;

constexpr int N_ = 131072;
constexpr int K_ = 64;
constexpr int D_ = 256;
constexpr int BM = 128;                 // rows per block
constexpr int NBLK = N_ / BM;           // 1024 blocks
constexpr int SQLD = 68;                // padded sq row stride (floats)

// ---------- helpers ----------
__device__ __forceinline__ ushort_t f2bf(float v) {
  unsigned u = __float_as_uint(v);
  u += 0x7FFFu + ((u >> 16) & 1u);  // RNE
  return (ushort_t)(u >> 16);
}

__device__ __forceinline__ void gld16(const ushort_t* g, ushort_t* l) {
  __builtin_amdgcn_global_load_lds(
      (const __attribute__((address_space(1))) unsigned int*)g,
      (__attribute__((address_space(3))) unsigned int*)l, 16, 0, 0);
}

// 16-lane (lc-group) sum, VALU-only DPP tree.
__device__ __forceinline__ float dpp_red16(float v) {
  int x = __float_as_int(v);
  v += __int_as_float(__builtin_amdgcn_update_dpp(0, x, 0xB1, 0xF, 0xF, true));
  x = __float_as_int(v);
  v += __int_as_float(__builtin_amdgcn_update_dpp(0, x, 0x4E, 0xF, 0xF, true));
  x = __float_as_int(v);
  v += __int_as_float(__builtin_amdgcn_update_dpp(0, x, 0x141, 0xF, 0xF, true));
  x = __float_as_int(v);
  v += __int_as_float(__builtin_amdgcn_update_dpp(0, x, 0x140, 0xF, 0xF, true));
  return v;
}

// ---------- prep: X fp32 -> bf16 A-fragment image ----------
// e = ((T*8 + mm)*8 + kc)*512 + lane*8 + j  holds
//   bf16( X[T*128 + mm*16 + (lane&15)][kc*32 + (lane>>4)*8 + j] )
__global__ void prep_x(const float* __restrict__ X, ushort_t* __restrict__ Xb) {
  for (int e = blockIdx.x * blockDim.x + threadIdx.x; e < N_ * D_;
       e += gridDim.x * blockDim.x) {
    int j = e & 7;
    int lane = (e >> 3) & 63;
    int kc = (e >> 9) & 7;
    int mm = (e >> 12) & 7;
    int T = e >> 15;
    int row = T * 128 + mm * 16 + (lane & 15);
    int col = kc * 32 + (lane >> 4) * 8 + j;
    Xb[e] = f2bf(X[(size_t)row * D_ + col]);
  }
}

// ---------- prep: P fp32 -> bf16 B substep image (BK=32) ----------
// e = (g*16 + wc*4 + n)*512 + lane*8 + j,  g = k*8 + s,  holds
//   bf16( P[k][s*32 + (lane>>4)*8 + j][wc*64 + n*16 + (lane&15)] )
__global__ void prep_p(const float* __restrict__ P, ushort_t* __restrict__ Pb) {
  for (int e = blockIdx.x * blockDim.x + threadIdx.x; e < K_ * D_ * D_;
       e += gridDim.x * blockDim.x) {
    int j = e & 7;
    int lane = (e >> 3) & 63;
    int n = (e >> 9) & 3;
    int wc = (e >> 11) & 3;
    int g = e >> 13;
    int k = g >> 3, s = g & 7;
    int row_p = s * 32 + (lane >> 4) * 8 + j;
    int col_p = wc * 64 + n * 16 + (lane & 15);
    Pb[e] = f2bf(P[((size_t)k * D_ + row_p) * D_ + col_p]);
  }
}

// ---------- prep: tvb[k][j] = bf16(sum_i mu[k][i]*P[k][i][j]); C[k] ----
__global__ void prep_t(const float* __restrict__ P, const float* __restrict__ mu,
                       const float* __restrict__ w, ushort_t* __restrict__ tvb,
                       float* __restrict__ C) {
  int k = blockIdx.x, j = threadIdx.x;
  const float* Pk = P + (size_t)k * D_ * D_;
  const float* muk = mu + (size_t)k * D_;
  float acc = 0.f;
  for (int i = 0; i < D_; ++i) acc += muk[i] * Pk[(size_t)i * D_ + j];
  tvb[k * D_ + j] = f2bf(acc);
  __shared__ float red[D_];
  red[j] = logf(Pk[(size_t)j * D_ + j]);
  __syncthreads();
  for (int s = 128; s > 0; s >>= 1) {
    if (j < s) red[j] += red[j + s];
    __syncthreads();
  }
  if (j == 0)
    C[k] = red[0] + logf(w[k]) - 0.5f * (float)D_ * logf(2.0f * (float)M_PI);
}

// ---------- main ----------
__global__ __launch_bounds__(512, 2) void gmm_main(
    const ushort_t* __restrict__ Xb, const ushort_t* __restrict__ Pb,
    const ushort_t* __restrict__ tvb,
    float* __restrict__ wlp /* [N][K], raw sq written */) {
  __shared__ __align__(16) ushort_t Bl[2][16384];  // 64 KiB: 2 pairs of substeps
  __shared__ __align__(16) ushort_t tvl[16384];    // 32 KiB bf16 tvec
  __shared__ float sqf[BM * SQLD];                 // 34.8 KiB accumulator

  const int tid = threadIdx.x;
  const int T = blockIdx.x;
  const int lane = tid & 63, wid = tid >> 6;
  const int wr = wid >> 2, wc = wid & 3;  // wave tile: 64 rows x 64 cols
  const int lc = lane & 15, lg = lane >> 4;

  // zero sq accumulator (128*68 = 8704 floats, 17/thread)
#pragma unroll
  for (int i = 0; i < 17; ++i) sqf[tid + i * 512] = 0.f;

  // ---- A fragments in registers: 32 x bf16x8 (AGPR-allocated) ----
  const ushort_t* Ag = Xb + (size_t)T * 32768;
  bf16x8 Areg[32];  // index m*8 + s (s = 32-wide k-chunk)
#pragma unroll
  for (int m = 0; m < 4; ++m)
#pragma unroll
    for (int c = 0; c < 8; ++c)
      Areg[m * 8 + c] =
          *(const bf16x8*)&Ag[(((wr * 4 + m) * 8 + c) * 512) + lane * 8];

  // ---- stage tvec (32 KB) + first pair (substeps 0,1) into Bl[0] ----
#pragma unroll
  for (int it = 0; it < 4; ++it)
    gld16(tvb + (it * 512 + tid) * 8, &tvl[(it * 512 + tid) * 8]);
#pragma unroll
  for (int it = 0; it < 4; ++it)
    gld16(Pb + (it * 512 + tid) * 8, &Bl[0][(it * 512 + tid) * 8]);

  asm volatile("s_waitcnt vmcnt(0) lgkmcnt(0)" ::: "memory");
  __builtin_amdgcn_s_barrier();

#pragma unroll 1
  for (int k = 0; k < K_; ++k) {
    // tv loads (LDS): overlap with staging issue below
    float tv[4];
#pragma unroll
    for (int n = 0; n < 4; ++n) {
      ushort_t uv = tvl[k * 256 + wc * 64 + n * 16 + lc];
      tv[n] = __uint_as_float((unsigned)uv << 16);
    }

    f32x4 acc[4][4];
#pragma unroll
    for (int m = 0; m < 4; ++m)
#pragma unroll
      for (int n = 0; n < 4; ++n) acc[m][n] = (f32x4){0.f, 0.f, 0.f, 0.f};

#pragma unroll
    for (int p = 0; p < 4; ++p) {
      const int cur = p & 1;  // k*4 is even, so pair parity == p&1
      // ---- stage NEXT pair (substeps G+2, G+3) into Bl[cur^1].
      // Safe: Bl[cur^1]'s last readers finished before the previous
      // period's end-of-period barrier (program order), which all waves
      // have passed. Unconditional: Pb slack (32 KiB) covers the final
      // over-stage (substeps 512, 513).
      {
        const ushort_t* gb = Pb + ((size_t)(k * 8 + 2 * p) + 2) * 8192;
        ushort_t* db = &Bl[cur ^ 1][0];
#pragma unroll
        for (int it = 0; it < 4; ++it)
          gld16(gb + (it * 512 + tid) * 8, db + (it * 512 + tid) * 8);
      }

      // ---- compute both substeps of the current pair (32 MFMA);
      // both substeps' B-frags are valid at period entry, so the
      // second substep's ds_reads can hoist into the first's MFMAs.
#pragma unroll
      for (int h = 0; h < 2; ++h) {
        const int s = 2 * p + h;
        bf16x8 bb[4];
#pragma unroll
        for (int n = 0; n < 4; ++n)
          bb[n] = *(const bf16x8*)&Bl[cur]
                      [h * 8192 + (wc * 4 + n) * 512 + lane * 8];
#pragma unroll
        for (int m = 0; m < 4; ++m)
#pragma unroll
          for (int n = 0; n < 4; ++n)
            acc[m][n] = __builtin_amdgcn_mfma_f32_16x16x32_bf16(
                Areg[m * 8 + s], bb[n], acc[m][n], 0, 0, 0);
      }

      // ---- epilogue on the last period of this k, before the drain:
      // its VALU hides the staged loads' latency.
      if (p == 3) {
#pragma unroll
        for (int m = 0; m < 4; ++m)
#pragma unroll
          for (int r = 0; r < 4; ++r) {
            float d0 = acc[m][0][r] - tv[0];
            float d1 = acc[m][1][r] - tv[1];
            float d2 = acc[m][2][r] - tv[2];
            float d3 = acc[m][3][r] - tv[3];
            float sfl = dpp_red16(d0 * d0 + d1 * d1 + d2 * d2 + d3 * d3);
            if (lc == 0) {
              int row = wr * 64 + m * 16 + lg * 4 + r;
              atomicAdd(&sqf[row * SQLD + k], sfl);
            }
          }
      }

      // ---- one drain + barrier per period (4 per k)
      asm volatile("s_waitcnt vmcnt(0)" ::: "memory");
      __builtin_amdgcn_s_barrier();
    }
  }

  __syncthreads();  // all ds_adds visible

  // flush: sq[128][64] -> wlp, coalesced f32x4
  float* dst = wlp + (size_t)T * BM * K_;
#pragma unroll
  for (int i = 0; i < 4; ++i) {
    int idx4 = tid + i * 512;
    int row = idx4 >> 4, c4 = idx4 & 15;
    ((f32x4*)dst)[idx4] = *(const f32x4*)&sqf[row * SQLD + c4 * 4];
  }
}

// ---------- LSE over k: scale partials, logsumexp, write log_resp ------
__global__ void lse_k(float* __restrict__ out, const float* __restrict__ C,
                      float* __restrict__ partial) {
  const int row = blockIdx.x * 256 + threadIdx.x;
  float* w = out + 1 + (size_t)row * K_;
  float v[K_];
  float mx = -1e30f;
#pragma unroll
  for (int j = 0; j < K_; ++j) {
    v[j] = -0.5f * w[j] + C[j];
    mx = fmaxf(mx, v[j]);
  }
  float ssum = 0.f;
#pragma unroll
  for (int j = 0; j < K_; ++j) ssum += expf(v[j] - mx);
  float l = mx + logf(ssum);
#pragma unroll
  for (int j = 0; j < K_; ++j) w[j] = v[j] - l;
  __shared__ float red[256];
  red[threadIdx.x] = l;
  __syncthreads();
  for (int s = 128; s > 0; s >>= 1) {
    if (threadIdx.x < s) red[threadIdx.x] += red[threadIdx.x + s];
    __syncthreads();
  }
  if (threadIdx.x == 0) partial[blockIdx.x] = red[0];
}

__global__ void final_red(const float* __restrict__ partial,
                          float* __restrict__ out) {
  __shared__ float red[512];
  red[threadIdx.x] = partial[threadIdx.x];
  __syncthreads();
  for (int s = 256; s > 0; s >>= 1) {
    if (threadIdx.x < s) red[threadIdx.x] += red[threadIdx.x + s];
    __syncthreads();
  }
  if (threadIdx.x == 0) out[0] = red[0] * (1.0f / (float)N_);
}

extern "C" void kernel_launch(void* const* d_in, const int* in_sizes, int n_in,
                              void* d_out, int out_size, void* d_ws,
                              size_t ws_size, hipStream_t stream) {
  const float* X = (const float*)d_in[0];
  const float* w = (const float*)d_in[1];
  const float* mu = (const float*)d_in[2];
  const float* P = (const float*)d_in[3];
  float* out = (float*)d_out;
  char* ws = (char*)d_ws;

  // ws layout (bytes) — total 75,565,312
  ushort_t* Xb = (ushort_t*)ws;                 // 67,108,864
  ushort_t* Pb = (ushort_t*)(ws + 67108864);    // 8,388,608 + 32,768 slack
  ushort_t* tvb = (ushort_t*)(ws + 75530240);   // 32,768 (bf16 tvec)
  float* C = (float*)(ws + 75563008);           // 256
  float* partial = (float*)(ws + 75563264);     // 2,048

  prep_x<<<2048, 256, 0, stream>>>(X, Xb);
  prep_p<<<2048, 256, 0, stream>>>(P, Pb);
  prep_t<<<K_, 256, 0, stream>>>(P, mu, w, tvb, C);
  gmm_main<<<NBLK, 512, 0, stream>>>(Xb, Pb, tvb, out + 1);
  lse_k<<<N_ / 256, 256, 0, stream>>>(out, C, partial);
  final_red<<<1, 512, 0, stream>>>(partial, out);
}